// Round 7
// baseline (277.627 us; speedup 1.0000x reference)
//
#include <hip/hip_runtime.h>
#include <math.h>

#define BATCH 64
#define HIMG 224
#define WIMG 224
#define IMGPLANE (HIMG*WIMG)   // 50176
#define CF 512
#define HF 28
#define WF 28
#define POS (HF*WF)            // 784
#define ALPHA_C 0.15f
#define EPS_C 1e-6f

#define STRIPS 14              // 16-row strips per sample
#define SROWS 16
#define GROWS 20               // SROWS + 4 halo rows
#define GSTR 229               // LDS row stride for gray (odd)
#define VSTR 261               // LDS row stride for var (swizzled cols)
#define SHN 4580               // max(GROWS*GSTR=4580, SROWS*VSTR=4176)

#define NATTN 512              // 64 samples x 8 channel-groups (clean 8 blocks/sample)
#define NVARH (STRIPS*BATCH)   // 896
// interleave: groups of 11 blocks = 4 attn + 7 varh (1408 = 128*11)

// ---- ws layout (in floats) ----
#define OFF_HRES 0
#define HRES_CNT (BATCH*HIMG*WF)             // 401,408
#define OFF_BMM  (OFF_HRES + HRES_CNT)       // per-strip [min,max]
#define OFF_AP   (OFF_BMM + BATCH*STRIPS*2)  // 8*BATCH*POS partial channel sums
#define OFF_ACC  (OFF_AP + 8*BATCH*POS)      // loss accumulator        (memset 0)
#define OFF_CNT  (OFF_ACC + 1)               // sample done counter     (memset 0)
#define OFF_SCNT (OFF_CNT + 1)               // 64 per-sample counters  (memset 0)

typedef float f4v __attribute__((ext_vector_type(4)));

// Non-temporal 16B load (round-6: fat_k dropped below the fill kernel's
// 59.4 us after adding these -> keep). Zero-reuse streams; nt relaxes L1.
__device__ __forceinline__ f4v nt4(const float* p) {
    return __builtin_nontemporal_load((const f4v*)p);
}

// Merged kernel. Round-1's merge failed from pinned-batch spills + 26 KB LDS;
// this one keeps the proven round-6 branch bodies (VGPR 32, LDS 18.4 KB) and
// an epilogue that reads hres from GLOBAL (no LDS growth). 22 blocks/sample
// (8 attn + 14 varh); 22nd arrival runs the per-sample epilogue, overlapping
// the grid's drain tail and eliminating the fused_k dispatch + gap.
__global__ __launch_bounds__(256, 2) void fat_k(const float* __restrict__ img,
                                                const float* __restrict__ f,
                                                float* __restrict__ ws,
                                                float* __restrict__ out) {
    __shared__ float sh[SHN];   // gray, later overlaid with var (18,320 B)
    __shared__ float wred[8];
    __shared__ float s_mn, s_mx;
    __shared__ int s_fin;
    int bid = blockIdx.x;
    int tid = threadIdx.x;
    int g11 = bid / 11, r11 = bid - 11 * g11;
    int bsmp;

    if (r11 < 4) {
        // -------- attn branch: (b, 64-channel group z), float4 over p --------
        int ab = g11 * 4 + r11;
        bsmp = ab >> 3;
        if (tid < 196) {        // 196 float4 per plane
            int z = ab & 7;
            const float* fp = f + (size_t)(bsmp * CF + z * 64) * POS + 4 * tid;
            float ax = 0.0f, ay = 0.0f, az = 0.0f, aw = 0.0f;
            // ascending channel order 0..63 -> summation order identical to
            // round-0 baseline (absmax 0).
            #pragma unroll
            for (int c = 0; c < 64; c++) {
                f4v u = nt4(fp + (size_t)c * POS);
                ax += u.x * u.x; ay += u.y * u.y;
                az += u.z * u.z; aw += u.w * u.w;
            }
            float4 o = make_float4(ax, ay, az, aw);
            *(float4*)(ws + OFF_AP + (size_t)((ab & 7) * BATCH + bsmp) * POS + 4 * tid) = o;
        }
    } else {
        // -------- varh branch --------
        int vb = g11 * 7 + (r11 - 4);
        int b = vb / STRIPS, sy = vb - b * STRIPS;
        bsmp = b;
        int y0 = sy * SROWS;
        const float* imb = img + (size_t)b * 3 * IMGPLANE;

        // stage gray interior via float4 (rows 16B-aligned: 224 floats/row)
        for (int i = tid; i < GROWS * 56; i += 256) {
            int gr = i / 56, q = i - gr * 56;
            int gy = y0 - 2 + gr;
            float gx0 = 0.0f, gx1 = 0.0f, gx2 = 0.0f, gx3 = 0.0f;
            if ((unsigned)gy < HIMG) {
                const float* row = imb + gy * WIMG + 4 * q;
                f4v a = nt4(row);
                f4v bb = nt4(row + IMGPLANE);
                f4v c = nt4(row + 2 * IMGPLANE);
                gx0 = 0.299f * a.x + 0.587f * bb.x + 0.114f * c.x;
                gx1 = 0.299f * a.y + 0.587f * bb.y + 0.114f * c.y;
                gx2 = 0.299f * a.z + 0.587f * bb.z + 0.114f * c.z;
                gx3 = 0.299f * a.w + 0.587f * bb.w + 0.114f * c.w;
            }
            int base = gr * GSTR + 2 + 4 * q;
            sh[base] = gx0; sh[base + 1] = gx1; sh[base + 2] = gx2; sh[base + 3] = gx3;
        }
        // zero gray col-halo (cols 0,1,226,227)
        if (tid < GROWS * 4) {
            int gr = tid >> 2, p = tid & 3;
            int gc = (p < 2) ? p : (224 + p);
            sh[gr * GSTR + gc] = 0.0f;
        }
        __syncthreads();

        // var into registers: thread (r = tid>>4, 14-col segment s = tid&15)
        int r = tid >> 4, s = tid & 15;
        int x0 = 14 * s;
        const float* gr0 = sh + r * GSTR;
        float c1[5], c2[5], vreg[14];
        #pragma unroll
        for (int m = 0; m < 5; m++) {
            float a = 0.0f, a2 = 0.0f;
            #pragma unroll
            for (int k = 0; k < 5; k++) {
                float u = gr0[k * GSTR + x0 + m];
                a += u; a2 += u * u;
            }
            c1[m] = a; c2[m] = a2;
        }
        float vmn = INFINITY, vmx = 0.0f;
        #pragma unroll
        for (int xi = 0; xi < 14; xi++) {
            int p = xi % 5;
            float s1 = c1[p], s2 = c2[p];
            #pragma unroll
            for (int m = 1; m < 5; m++) {
                s1 += c1[(p + m) % 5];
                s2 += c2[(p + m) % 5];
            }
            float m1 = s1 * 0.04f, m2 = s2 * 0.04f;
            float vv = fmaxf(m2 - m1 * m1, 0.0f);
            vreg[xi] = vv;
            vmn = fminf(vmn, vv); vmx = fmaxf(vmx, vv);
            if (xi < 13) {
                float a = 0.0f, a2 = 0.0f;
                #pragma unroll
                for (int k = 0; k < 5; k++) {
                    float u = gr0[k * GSTR + x0 + xi + 5];
                    a += u; a2 += u * u;
                }
                c1[p] = a; c2[p] = a2;
            }
        }
        #pragma unroll
        for (int o = 32; o > 0; o >>= 1) {
            vmn = fminf(vmn, __shfl_xor(vmn, o));
            vmx = fmaxf(vmx, __shfl_xor(vmx, o));
        }
        __syncthreads();   // all gray reads done -> safe to overlay with var
        int w = tid >> 6;
        if ((tid & 63) == 0) { wred[w] = vmn; wred[4 + w] = vmx; }
        // zero var col-halo (jh 0..3 and 228..231)
        if (tid < SROWS * 8) {
            int rr = tid >> 3, p = tid & 7;
            int jh = p + ((p < 4) ? 0 : 224);
            sh[rr * VSTR + jh + (jh >> 3)] = 0.0f;
        }
        // write var registers into overlaid buffer (swizzled cols)
        #pragma unroll
        for (int xi = 0; xi < 14; xi++) {
            int jh = x0 + xi + 4;
            sh[r * VSTR + jh + (jh >> 3)] = vreg[xi];
        }
        __syncthreads();   // var + wred ready
        if (tid == 0) {
            float mn = fminf(fminf(wred[0], wred[1]), fminf(wred[2], wred[3]));
            float mx = fmaxf(fmaxf(wred[4], wred[5]), fmaxf(wred[6], wred[7]));
            int blk = b * STRIPS + sy;
            ws[OFF_BMM + 2 * blk]     = mn;
            ws[OFF_BMM + 2 * blk + 1] = mx;
        }

        // horizontal 16-tap resize from LDS var; coalesced store of hres strip
        float* hb = ws + OFF_HRES + ((size_t)b * HIMG + y0) * WF;
        for (int idx = tid; idx < SROWS * WF; idx += 256) {   // 448
            int rr = idx / WF, i = idx - rr * WF;
            float acc = 0.0f, wsum = 0.0f;
            int j0 = 8 * i - 4;
            #pragma unroll
            for (int t = 0; t < 16; t++) {
                int j = j0 + t;
                float w_ = 8.0f - fabsf((float)t - 7.5f);
                int jh = j + 4;
                acc += w_ * sh[rr * VSTR + jh + (jh >> 3)];   // halo = 0 -> exact
                if ((unsigned)j < WIMG) wsum += w_;
            }
            hb[idx] = acc / wsum;
        }
    }

    // ---- completion: 22 blocks/sample. Last arrival runs the epilogue. ----
    __syncthreads();                       // all waves' global stores drained (vmcnt0 before barrier)
    if (tid == 0) {
        __threadfence();                   // release to device scope
        unsigned old = atomicAdd((unsigned*)ws + OFF_SCNT + bsmp, 1u);
        s_fin = (old == 21u) ? 1 : 0;
    }
    __syncthreads();
    if (!s_fin) return;
    __threadfence();                       // acquire: all 22 blocks' writes visible

    int b = bsmp;

    // 1) var min/max from 14 per-strip pairs (first wave)
    if (tid < 64) {
        float mn = INFINITY, mx = 0.0f;
        if (tid < STRIPS) {
            mn = ws[OFF_BMM + 2 * (b * STRIPS + tid)];
            mx = ws[OFF_BMM + 2 * (b * STRIPS + tid) + 1];
        }
        #pragma unroll
        for (int o = 8; o > 0; o >>= 1) {
            mn = fminf(mn, __shfl_down(mn, o));
            mx = fmaxf(mx, __shfl_down(mx, o));
        }
        if (tid == 0) { s_mn = mn; s_mx = mx; }
    }
    __syncthreads();
    float vmn = s_mn, vmx = s_mx;
    float vden = vmx - vmn;
    bool vok = vden > EPS_C;

    // 2) vertical resize (hres from global, L2-hot) -> sal; attn from 8 partials
    const float* hg = ws + OFF_HRES + (size_t)b * HIMG * WF;
    const float* ap = ws + OFF_AP + (size_t)b * POS;
    float salv[4], attnv[4];
    float amn = INFINITY, amx = -INFINITY;
    #pragma unroll
    for (int k = 0; k < 4; k++) {
        int idx = tid + 256 * k;
        salv[k] = 0.0f; attnv[k] = 0.0f;
        if (idx < POS) {
            int yo = idx / WF, x = idx - yo * WF;
            float acc = 0.0f, wsum = 0.0f;
            int j0 = 8 * yo - 4;
            #pragma unroll
            for (int t = 0; t < 16; t++) {
                int j = j0 + t;
                float w = 8.0f - fabsf((float)t - 7.5f);
                if ((unsigned)j < HIMG) { acc += w * hg[j * WF + x]; wsum += w; }
            }
            float sraw = acc / wsum;
            salv[k] = vok ? (sraw - vmn) / vden : 0.5f;
            float ssum = 0.0f;
            #pragma unroll
            for (int z = 0; z < 8; z++)        // ascending z => c order 0..511
                ssum += ap[(size_t)z * BATCH * POS + idx];
            float a = sqrtf(ssum * (1.0f / CF));
            attnv[k] = a;
            amn = fminf(amn, a); amx = fmaxf(amx, a);
        }
    }

    // 3) block min/max of attn (one pass through wred[8])
    #pragma unroll
    for (int o = 32; o > 0; o >>= 1) {
        amn = fminf(amn, __shfl_xor(amn, o));
        amx = fmaxf(amx, __shfl_xor(amx, o));
    }
    int wv = tid >> 6;
    if ((tid & 63) == 0) { wred[wv] = amn; wred[4 + wv] = amx; }
    __syncthreads();
    if (tid == 0) {
        s_mn = fminf(fminf(wred[0], wred[1]), fminf(wred[2], wred[3]));
        s_mx = fmaxf(fmaxf(wred[4], wred[5]), fmaxf(wred[6], wred[7]));
    }
    __syncthreads();
    amn = s_mn; amx = s_mx;
    float aden = amx - amn;
    bool aok = aden > EPS_C;

    // 4) MSE partial
    float lsum = 0.0f;
    #pragma unroll
    for (int k = 0; k < 4; k++) {
        int idx = tid + 256 * k;
        if (idx < POS) {
            float an = aok ? (attnv[k] - amn) / aden : 0.5f;
            float d = an - salv[k];
            lsum += d * d;
        }
    }
    #pragma unroll
    for (int o = 32; o > 0; o >>= 1) lsum += __shfl_xor(lsum, o);
    if ((tid & 63) == 0) wred[wv] = lsum;
    __syncthreads();

    // 5) accumulate across samples; last finished sample writes output
    if (tid == 0) {
        float part = wred[0] + wred[1] + wred[2] + wred[3];
        atomicAdd(ws + OFF_ACC, part);
        __threadfence();
        unsigned old = atomicAdd((unsigned*)ws + OFF_CNT, 1u);
        if (old == BATCH - 1) {
            float tot = atomicAdd(ws + OFF_ACC, 0.0f);  // device-coherent read
            out[0] = tot * (ALPHA_C / (float)(BATCH * POS));
        }
    }
}

extern "C" void kernel_launch(void* const* d_in, const int* in_sizes, int n_in,
                              void* d_out, int out_size, void* d_ws, size_t ws_size,
                              hipStream_t stream) {
    const float* features = (const float*)d_in[0];  // [64,512,28,28]
    const float* images   = (const float*)d_in[1];  // [64,3,224,224]
    float* ws  = (float*)d_ws;
    float* out = (float*)d_out;

    // zero ACC + CNT + 64 per-sample counters (264 B; capture-legal)
    hipMemsetAsync((char*)d_ws + (size_t)OFF_ACC * sizeof(float), 0,
                   (2 + BATCH) * sizeof(unsigned), stream);
    hipLaunchKernelGGL(fat_k, dim3(NATTN + NVARH), dim3(256), 0, stream,
                       images, features, ws, out);
}

// Round 8
// 179.590 us; speedup vs baseline: 1.5459x; 1.5459x over previous
//
#include <hip/hip_runtime.h>
#include <math.h>

#define BATCH 64
#define HIMG 224
#define WIMG 224
#define IMGPLANE (HIMG*WIMG)   // 50176
#define CF 512
#define HF 28
#define WF 28
#define POS (HF*WF)            // 784
#define ALPHA_C 0.15f
#define EPS_C 1e-6f

#define STRIPS 14              // 16-row strips per sample
#define SROWS 16
#define GROWS 20               // SROWS + 4 halo rows
#define GCOLS 228              // 224 + 2+2 halo cols
#define GSTR 229               // LDS row stride for gray (odd)
#define VSTR 261               // LDS row stride for var (swizzled cols)
#define SHN 4580               // max(GROWS*GSTR=4580, SROWS*VSTR=4176)

#define NATTN 512              // 64 samples x 8 channel-groups
#define NVARH (STRIPS*BATCH)   // 896
// interleave: groups of 11 blocks = 4 attn + 7 varh (1408 = 128*11)

// ---- ws layout (in floats) ----
#define OFF_HRES 0
#define HRES_CNT (BATCH*HIMG*WF)             // 401,408
#define OFF_BMM (OFF_HRES + HRES_CNT)        // BATCH*STRIPS*2 per-strip [min,max]
#define OFF_AP  (OFF_BMM + BATCH*STRIPS*2)   // 8*BATCH*POS partial channel sums
#define OFF_ACC (OFF_AP + 8*BATCH*POS)       // loss accumulator
#define OFF_CNT (OFF_ACC + 1)                // done counter (uint slot)

typedef float f4v __attribute__((ext_vector_type(4)));

// Non-temporal 16B load: identical value, `nt` cache policy. Round-6 showed
// fat_k dropping below the 59.4us fill kernel with these; only change vs the
// proven 191.0us baseline. Zero-reuse streams -> relax L1/L2 retention.
__device__ __forceinline__ f4v nt4(const float* p) {
    return __builtin_nontemporal_load((const f4v*)p);
}

// NOTE (rounds 1,7): do NOT merge fused_k into this kernel. The per-block
// device-scope __threadfence() required for cross-XCD visibility writes back/
// invalidates the XCD's L2 under the streaming reads -> fat_k 59->145us.
// Kernel boundaries provide the coherence for free.
__global__ __launch_bounds__(256, 2) void fat_k(const float* __restrict__ img,
                                                const float* __restrict__ f,
                                                float* __restrict__ ws) {
    __shared__ float sh[SHN];   // gray, later overlaid with var (18,320 B)
    __shared__ float wred[8];
    int bid = blockIdx.x;
    int tid = threadIdx.x;
    int g11 = bid / 11, r11 = bid - 11 * g11;

    if (r11 < 4) {
        // -------- attn branch: (b, 64-channel group z), float4 over p --------
        int ab = g11 * 4 + r11;
        if (ab == 0 && tid == 0) {
            ws[OFF_ACC] = 0.0f;
            ((unsigned*)ws)[OFF_CNT] = 0u;
        }
        if (tid >= 196) return;     // 196 float4 per plane
        int b = ab >> 3, z = ab & 7;
        const float* fp = f + (size_t)(b * CF + z * 64) * POS + 4 * tid;
        float ax = 0.0f, ay = 0.0f, az = 0.0f, aw = 0.0f;
        #pragma unroll
        for (int cc = 0; cc < 64; cc += 16) {
            f4v u[16];
            #pragma unroll
            for (int j = 0; j < 16; j++)
                u[j] = nt4(fp + (size_t)(cc + j) * POS);
            #pragma unroll
            for (int j = 0; j < 16; j++) {
                ax += u[j].x * u[j].x; ay += u[j].y * u[j].y;
                az += u[j].z * u[j].z; aw += u[j].w * u[j].w;
            }
        }
        float4 o = make_float4(ax, ay, az, aw);
        *(float4*)(ws + OFF_AP + (size_t)(z * BATCH + b) * POS + 4 * tid) = o;
        return;
    }

    // -------- varh branch --------
    int vb = g11 * 7 + (r11 - 4);
    int b = vb / STRIPS, sy = vb - b * STRIPS;
    int y0 = sy * SROWS;
    const float* imb = img + (size_t)b * 3 * IMGPLANE;

    // stage gray interior via float4 (rows 16B-aligned: 224 floats/row)
    for (int i = tid; i < GROWS * 56; i += 256) {
        int gr = i / 56, q = i - gr * 56;
        int gy = y0 - 2 + gr;
        float gx0 = 0.0f, gx1 = 0.0f, gx2 = 0.0f, gx3 = 0.0f;
        if ((unsigned)gy < HIMG) {
            const float* row = imb + gy * WIMG + 4 * q;
            f4v a = nt4(row);
            f4v bb = nt4(row + IMGPLANE);
            f4v c = nt4(row + 2 * IMGPLANE);
            gx0 = 0.299f * a.x + 0.587f * bb.x + 0.114f * c.x;
            gx1 = 0.299f * a.y + 0.587f * bb.y + 0.114f * c.y;
            gx2 = 0.299f * a.z + 0.587f * bb.z + 0.114f * c.z;
            gx3 = 0.299f * a.w + 0.587f * bb.w + 0.114f * c.w;
        }
        int base = gr * GSTR + 2 + 4 * q;
        sh[base] = gx0; sh[base + 1] = gx1; sh[base + 2] = gx2; sh[base + 3] = gx3;
    }
    // zero gray col-halo (cols 0,1,226,227)
    if (tid < GROWS * 4) {
        int gr = tid >> 2, p = tid & 3;
        int gc = (p < 2) ? p : (224 + p);
        sh[gr * GSTR + gc] = 0.0f;
    }
    __syncthreads();

    // var into registers: thread (r = tid>>4, 14-col segment s = tid&15)
    int r = tid >> 4, s = tid & 15;
    int x0 = 14 * s;
    const float* gr0 = sh + r * GSTR;
    float c1[5], c2[5], vreg[14];
    #pragma unroll
    for (int m = 0; m < 5; m++) {
        float a = 0.0f, a2 = 0.0f;
        #pragma unroll
        for (int k = 0; k < 5; k++) {
            float u = gr0[k * GSTR + x0 + m];
            a += u; a2 += u * u;
        }
        c1[m] = a; c2[m] = a2;
    }
    float vmn = INFINITY, vmx = 0.0f;
    #pragma unroll
    for (int xi = 0; xi < 14; xi++) {
        int p = xi % 5;
        float s1 = c1[p], s2 = c2[p];
        #pragma unroll
        for (int m = 1; m < 5; m++) {
            s1 += c1[(p + m) % 5];
            s2 += c2[(p + m) % 5];
        }
        float m1 = s1 * 0.04f, m2 = s2 * 0.04f;
        float vv = fmaxf(m2 - m1 * m1, 0.0f);
        vreg[xi] = vv;
        vmn = fminf(vmn, vv); vmx = fmaxf(vmx, vv);
        if (xi < 13) {
            float a = 0.0f, a2 = 0.0f;
            #pragma unroll
            for (int k = 0; k < 5; k++) {
                float u = gr0[k * GSTR + x0 + xi + 5];
                a += u; a2 += u * u;
            }
            c1[p] = a; c2[p] = a2;
        }
    }
    #pragma unroll
    for (int o = 32; o > 0; o >>= 1) {
        vmn = fminf(vmn, __shfl_xor(vmn, o));
        vmx = fmaxf(vmx, __shfl_xor(vmx, o));
    }
    __syncthreads();   // all gray reads done -> safe to overlay with var
    int w = tid >> 6;
    if ((tid & 63) == 0) { wred[w] = vmn; wred[4 + w] = vmx; }
    // zero var col-halo (jh 0..3 and 228..231)
    if (tid < SROWS * 8) {
        int rr = tid >> 3, p = tid & 7;
        int jh = p + ((p < 4) ? 0 : 224);
        sh[rr * VSTR + jh + (jh >> 3)] = 0.0f;
    }
    // write var registers into overlaid buffer (swizzled cols)
    #pragma unroll
    for (int xi = 0; xi < 14; xi++) {
        int jh = x0 + xi + 4;
        sh[r * VSTR + jh + (jh >> 3)] = vreg[xi];
    }
    __syncthreads();   // var + wred ready
    if (tid == 0) {
        float mn = fminf(fminf(wred[0], wred[1]), fminf(wred[2], wred[3]));
        float mx = fmaxf(fmaxf(wred[4], wred[5]), fmaxf(wred[6], wred[7]));
        int blk = b * STRIPS + sy;
        ws[OFF_BMM + 2 * blk]     = mn;
        ws[OFF_BMM + 2 * blk + 1] = mx;
    }

    // horizontal 16-tap resize from LDS var; coalesced store of hres strip
    float* hb = ws + OFF_HRES + ((size_t)b * HIMG + y0) * WF;
    for (int idx = tid; idx < SROWS * WF; idx += 256) {   // 448
        int rr = idx / WF, i = idx - rr * WF;
        float acc = 0.0f, wsum = 0.0f;
        int j0 = 8 * i - 4;
        #pragma unroll
        for (int t = 0; t < 16; t++) {
            int j = j0 + t;
            float w_ = 8.0f - fabsf((float)t - 7.5f);
            int jh = j + 4;
            acc += w_ * sh[rr * VSTR + jh + (jh >> 3)];   // halo = 0 -> exact
            if ((unsigned)j < WIMG) wsum += w_;
        }
        hb[idx] = acc / wsum;
    }
}

// ---- per sample: minmax reduce, vertical 16-tap resize, attn norm, MSE, last-block finish ----
__global__ __launch_bounds__(256) void fused_k(float* __restrict__ ws,
                                               float* __restrict__ out) {
    __shared__ float hres[HIMG][WF + 1];   // 25,984 B
    __shared__ float wred[4];
    __shared__ float s_mn, s_mx;
    int b = blockIdx.x;
    int tid = threadIdx.x;

    // 1) reduce 14 per-strip var min/max pairs (first wave)
    if (tid < 64) {
        float mn = INFINITY, mx = 0.0f;
        if (tid < STRIPS) {
            mn = ws[OFF_BMM + 2 * (b * STRIPS + tid)];
            mx = ws[OFF_BMM + 2 * (b * STRIPS + tid) + 1];
        }
        #pragma unroll
        for (int o = 8; o > 0; o >>= 1) {
            mn = fminf(mn, __shfl_down(mn, o));
            mx = fmaxf(mx, __shfl_down(mx, o));
        }
        if (tid == 0) { s_mn = mn; s_mx = mx; }
    }

    // 2) stage hres (coalesced)
    const float* hg = ws + OFF_HRES + (size_t)b * HIMG * WF;
    for (int i = tid; i < HIMG * WF; i += 256) {
        int y = i / WF, x = i - y * WF;
        hres[y][x] = hg[i];
    }
    __syncthreads();

    float vmn = s_mn, vmx = s_mx;
    float vden = vmx - vmn;
    bool vok = vden > EPS_C;

    // 3) vertical resize -> sal (regs); attn from 8 partials (regs)
    const float* ap = ws + OFF_AP + (size_t)b * POS;
    float salv[4], attnv[4];
    float amn = INFINITY, amx = -INFINITY;
    #pragma unroll
    for (int k = 0; k < 4; k++) {
        int idx = tid + 256 * k;
        salv[k] = 0.0f; attnv[k] = 0.0f;
        if (idx < POS) {
            int yo = idx / WF, x = idx - yo * WF;
            float acc = 0.0f, wsum = 0.0f;
            int j0 = 8 * yo - 4;
            #pragma unroll
            for (int t = 0; t < 16; t++) {
                int j = j0 + t;
                float w = 8.0f - fabsf((float)t - 7.5f);
                if ((unsigned)j < HIMG) { acc += w * hres[j][x]; wsum += w; }
            }
            float sraw = acc / wsum;
            salv[k] = vok ? (sraw - vmn) / vden : 0.5f;
            float ssum = 0.0f;
            #pragma unroll
            for (int z = 0; z < 8; z++)
                ssum += ap[(size_t)z * BATCH * POS + idx];
            float a = sqrtf(ssum * (1.0f / CF));
            attnv[k] = a;
            amn = fminf(amn, a); amx = fmaxf(amx, a);
        }
    }

    // 4) block min/max of attn
    #pragma unroll
    for (int o = 32; o > 0; o >>= 1) {
        amn = fminf(amn, __shfl_xor(amn, o));
        amx = fmaxf(amx, __shfl_xor(amx, o));
    }
    int w = tid >> 6;
    if ((tid & 63) == 0) wred[w] = amn;
    __syncthreads();
    if (tid == 0) s_mn = fminf(fminf(wred[0], wred[1]), fminf(wred[2], wred[3]));
    __syncthreads();
    if ((tid & 63) == 0) wred[w] = amx;
    __syncthreads();
    if (tid == 0) s_mx = fmaxf(fmaxf(wred[0], wred[1]), fmaxf(wred[2], wred[3]));
    __syncthreads();
    amn = s_mn; amx = s_mx;
    float aden = amx - amn;
    bool aok = aden > EPS_C;

    // 5) MSE partial
    float lsum = 0.0f;
    #pragma unroll
    for (int k = 0; k < 4; k++) {
        int idx = tid + 256 * k;
        if (idx < POS) {
            float an = aok ? (attnv[k] - amn) / aden : 0.5f;
            float d = an - salv[k];
            lsum += d * d;
        }
    }
    #pragma unroll
    for (int o = 32; o > 0; o >>= 1) lsum += __shfl_xor(lsum, o);
    if ((tid & 63) == 0) wred[w] = lsum;
    __syncthreads();

    // 6) accumulate across blocks; last finished block writes output
    if (tid == 0) {
        float part = wred[0] + wred[1] + wred[2] + wred[3];
        atomicAdd(ws + OFF_ACC, part);
        __threadfence();
        unsigned old = atomicAdd((unsigned*)ws + OFF_CNT, 1u);
        if (old == BATCH - 1) {
            float tot = atomicAdd(ws + OFF_ACC, 0.0f);  // device-coherent read
            out[0] = tot * (ALPHA_C / (float)(BATCH * POS));
        }
    }
}

extern "C" void kernel_launch(void* const* d_in, const int* in_sizes, int n_in,
                              void* d_out, int out_size, void* d_ws, size_t ws_size,
                              hipStream_t stream) {
    const float* features = (const float*)d_in[0];  // [64,512,28,28]
    const float* images   = (const float*)d_in[1];  // [64,3,224,224]
    float* ws  = (float*)d_ws;
    float* out = (float*)d_out;

    hipLaunchKernelGGL(fat_k,   dim3(NATTN + NVARH), dim3(256), 0, stream,
                       images, features, ws);
    hipLaunchKernelGGL(fused_k, dim3(BATCH),         dim3(256), 0, stream, ws, out);
}

// Round 9
// 175.569 us; speedup vs baseline: 1.5813x; 1.0229x over previous
//
#include <hip/hip_runtime.h>
#include <math.h>

#define BATCH 64
#define HIMG 224
#define WIMG 224
#define IMGPLANE (HIMG*WIMG)   // 50176
#define CF 512
#define HF 28
#define WF 28
#define POS (HF*WF)            // 784
#define ALPHA_C 0.15f
#define EPS_C 1e-6f

#define STRIPS 14              // 16-row strips per sample
#define SROWS 16
#define GROWS 20               // SROWS + 4 halo rows
#define GCOLS 228              // 224 + 2+2 halo cols
#define GSTR 229               // LDS row stride for gray (odd)
#define VSTR 261               // LDS row stride for var (swizzled cols)
#define SHN 4580               // max(GROWS*GSTR=4580, SROWS*VSTR=4176)

#define NATTN 512              // 64 samples x 8 channel-groups
#define NVARH (STRIPS*BATCH)   // 896
// interleave: groups of 11 blocks = 4 attn + 7 varh (1408 = 128*11)

// ---- ws layout (in floats) ----
#define OFF_HRES 0
#define HRES_CNT (BATCH*HIMG*WF)             // 401,408
#define OFF_BMM (OFF_HRES + HRES_CNT)        // BATCH*STRIPS*2 per-strip [min,max]
#define OFF_AP  (OFF_BMM + BATCH*STRIPS*2)   // 8*BATCH*POS partial channel sums
#define OFF_ACC (OFF_AP + 8*BATCH*POS)       // loss accumulator
#define OFF_CNT (OFF_ACC + 1)                // done counter (uint slot)

typedef float f4v __attribute__((ext_vector_type(4)));

// Non-temporal 16B load: identical value, `nt` cache policy. Round-8 verified:
// baseline + nt = 191.0 -> 179.6 us (fat_k ~62.8 -> ~51, +22% read rate).
// Zero-reuse streams -> relax L1/L2 retention.
__device__ __forceinline__ f4v nt4(const float* p) {
    return __builtin_nontemporal_load((const f4v*)p);
}

// NOTE (rounds 1,7): do NOT merge fused_k into this kernel. The per-block
// device-scope __threadfence() required for cross-XCD visibility writes back/
// invalidates the XCD's L2 under the streaming reads -> fat_k 59->145us.
// Kernel boundaries provide the coherence for free.
__global__ __launch_bounds__(256, 2) void fat_k(const float* __restrict__ img,
                                                const float* __restrict__ f,
                                                float* __restrict__ ws) {
    __shared__ float sh[SHN];   // gray, later overlaid with var (18,320 B)
    __shared__ float wred[8];
    int bid = blockIdx.x;
    int tid = threadIdx.x;
    int g11 = bid / 11, r11 = bid - 11 * g11;

    if (r11 < 4) {
        // -------- attn branch: (b, 64-channel group z), float4 over p --------
        int ab = g11 * 4 + r11;
        if (ab == 0 && tid == 0) {
            ws[OFF_ACC] = 0.0f;
            ((unsigned*)ws)[OFF_CNT] = 0u;
        }
        if (tid >= 196) return;     // 196 float4 per plane
        int b = ab >> 3, z = ab & 7;
        const float* fp = f + (size_t)(b * CF + z * 64) * POS + 4 * tid;
        float ax = 0.0f, ay = 0.0f, az = 0.0f, aw = 0.0f;
        #pragma unroll
        for (int cc = 0; cc < 64; cc += 16) {
            f4v u[16];
            #pragma unroll
            for (int j = 0; j < 16; j++)
                u[j] = nt4(fp + (size_t)(cc + j) * POS);
            #pragma unroll
            for (int j = 0; j < 16; j++) {
                ax += u[j].x * u[j].x; ay += u[j].y * u[j].y;
                az += u[j].z * u[j].z; aw += u[j].w * u[j].w;
            }
        }
        float4 o = make_float4(ax, ay, az, aw);
        *(float4*)(ws + OFF_AP + (size_t)(z * BATCH + b) * POS + 4 * tid) = o;
        return;
    }

    // -------- varh branch --------
    int vb = g11 * 7 + (r11 - 4);
    int b = vb / STRIPS, sy = vb - b * STRIPS;
    int y0 = sy * SROWS;
    const float* imb = img + (size_t)b * 3 * IMGPLANE;

    // stage gray interior via float4 (rows 16B-aligned: 224 floats/row)
    for (int i = tid; i < GROWS * 56; i += 256) {
        int gr = i / 56, q = i - gr * 56;
        int gy = y0 - 2 + gr;
        float gx0 = 0.0f, gx1 = 0.0f, gx2 = 0.0f, gx3 = 0.0f;
        if ((unsigned)gy < HIMG) {
            const float* row = imb + gy * WIMG + 4 * q;
            f4v a = nt4(row);
            f4v bb = nt4(row + IMGPLANE);
            f4v c = nt4(row + 2 * IMGPLANE);
            gx0 = 0.299f * a.x + 0.587f * bb.x + 0.114f * c.x;
            gx1 = 0.299f * a.y + 0.587f * bb.y + 0.114f * c.y;
            gx2 = 0.299f * a.z + 0.587f * bb.z + 0.114f * c.z;
            gx3 = 0.299f * a.w + 0.587f * bb.w + 0.114f * c.w;
        }
        int base = gr * GSTR + 2 + 4 * q;
        sh[base] = gx0; sh[base + 1] = gx1; sh[base + 2] = gx2; sh[base + 3] = gx3;
    }
    // zero gray col-halo (cols 0,1,226,227)
    if (tid < GROWS * 4) {
        int gr = tid >> 2, p = tid & 3;
        int gc = (p < 2) ? p : (224 + p);
        sh[gr * GSTR + gc] = 0.0f;
    }
    __syncthreads();

    // var into registers: thread (r = tid>>4, 14-col segment s = tid&15)
    int r = tid >> 4, s = tid & 15;
    int x0 = 14 * s;
    const float* gr0 = sh + r * GSTR;
    float c1[5], c2[5], vreg[14];
    #pragma unroll
    for (int m = 0; m < 5; m++) {
        float a = 0.0f, a2 = 0.0f;
        #pragma unroll
        for (int k = 0; k < 5; k++) {
            float u = gr0[k * GSTR + x0 + m];
            a += u; a2 += u * u;
        }
        c1[m] = a; c2[m] = a2;
    }
    float vmn = INFINITY, vmx = 0.0f;
    #pragma unroll
    for (int xi = 0; xi < 14; xi++) {
        int p = xi % 5;
        float s1 = c1[p], s2 = c2[p];
        #pragma unroll
        for (int m = 1; m < 5; m++) {
            s1 += c1[(p + m) % 5];
            s2 += c2[(p + m) % 5];
        }
        float m1 = s1 * 0.04f, m2 = s2 * 0.04f;
        float vv = fmaxf(m2 - m1 * m1, 0.0f);
        vreg[xi] = vv;
        vmn = fminf(vmn, vv); vmx = fmaxf(vmx, vv);
        if (xi < 13) {
            float a = 0.0f, a2 = 0.0f;
            #pragma unroll
            for (int k = 0; k < 5; k++) {
                float u = gr0[k * GSTR + x0 + xi + 5];
                a += u; a2 += u * u;
            }
            c1[p] = a; c2[p] = a2;
        }
    }
    #pragma unroll
    for (int o = 32; o > 0; o >>= 1) {
        vmn = fminf(vmn, __shfl_xor(vmn, o));
        vmx = fmaxf(vmx, __shfl_xor(vmx, o));
    }
    __syncthreads();   // all gray reads done -> safe to overlay with var
    int w = tid >> 6;
    if ((tid & 63) == 0) { wred[w] = vmn; wred[4 + w] = vmx; }
    // zero var col-halo (jh 0..3 and 228..231)
    if (tid < SROWS * 8) {
        int rr = tid >> 3, p = tid & 7;
        int jh = p + ((p < 4) ? 0 : 224);
        sh[rr * VSTR + jh + (jh >> 3)] = 0.0f;
    }
    // write var registers into overlaid buffer (swizzled cols)
    #pragma unroll
    for (int xi = 0; xi < 14; xi++) {
        int jh = x0 + xi + 4;
        sh[r * VSTR + jh + (jh >> 3)] = vreg[xi];
    }
    __syncthreads();   // var + wred ready
    if (tid == 0) {
        float mn = fminf(fminf(wred[0], wred[1]), fminf(wred[2], wred[3]));
        float mx = fmaxf(fmaxf(wred[4], wred[5]), fmaxf(wred[6], wred[7]));
        int blk = b * STRIPS + sy;
        ws[OFF_BMM + 2 * blk]     = mn;
        ws[OFF_BMM + 2 * blk + 1] = mx;
    }

    // horizontal 16-tap resize from LDS var; coalesced store of hres strip
    float* hb = ws + OFF_HRES + ((size_t)b * HIMG + y0) * WF;
    for (int idx = tid; idx < SROWS * WF; idx += 256) {   // 448
        int rr = idx / WF, i = idx - rr * WF;
        float acc = 0.0f, wsum = 0.0f;
        int j0 = 8 * i - 4;
        #pragma unroll
        for (int t = 0; t < 16; t++) {
            int j = j0 + t;
            float w_ = 8.0f - fabsf((float)t - 7.5f);
            int jh = j + 4;
            acc += w_ * sh[rr * VSTR + jh + (jh >> 3)];   // halo = 0 -> exact
            if ((unsigned)j < WIMG) wsum += w_;
        }
        hb[idx] = acc / wsum;
    }
}

// ---- per sample: minmax reduce, vertical resize, attn norm, MSE ----
// Round-9 change: fused_k was 17us for 4.8 MB (280 GB/s) built of ~75 scalar
// 4B loads/thread. WF=28 is 4-divisible -> float4 everything: hres staging
// (1568 xfloat4) and ap partial reads (thread owns 4 consecutive positions,
// 8 xfloat4). Per-element arithmetic (tap order, z order) bitwise identical;
// only lsum/minmax reduction association changes (~1e-9 on the loss).
__global__ __launch_bounds__(256) void fused_k(float* __restrict__ ws,
                                               float* __restrict__ out) {
    __shared__ float hres[HIMG][WF + 1];   // 26,096 B
    __shared__ float wred[8];
    __shared__ float s_mn, s_mx;
    int b = blockIdx.x;
    int tid = threadIdx.x;

    // 1) reduce 14 per-strip var min/max pairs (first wave)
    if (tid < 64) {
        float mn = INFINITY, mx = 0.0f;
        if (tid < STRIPS) {
            mn = ws[OFF_BMM + 2 * (b * STRIPS + tid)];
            mx = ws[OFF_BMM + 2 * (b * STRIPS + tid) + 1];
        }
        #pragma unroll
        for (int o = 8; o > 0; o >>= 1) {
            mn = fminf(mn, __shfl_down(mn, o));
            mx = fmaxf(mx, __shfl_down(mx, o));
        }
        if (tid == 0) { s_mn = mn; s_mx = mx; }
    }

    // 2) stage hres via float4 (7 quads per 28-wide row)
    const float* hg = ws + OFF_HRES + (size_t)b * HIMG * WF;
    for (int i4 = tid; i4 < HIMG * 7; i4 += 256) {
        f4v v = nt4(hg + 4 * (size_t)i4);
        int y = i4 / 7, x4 = (i4 - y * 7) * 4;
        hres[y][x4]     = v.x; hres[y][x4 + 1] = v.y;
        hres[y][x4 + 2] = v.z; hres[y][x4 + 3] = v.w;
    }
    __syncthreads();

    float vmn = s_mn, vmx = s_mx;
    float vden = vmx - vmn;
    bool vok = vden > EPS_C;

    // 3) thread owns 4 consecutive positions idx0..idx0+3 (same row yo):
    //    vertical 16-tap resize from LDS + attn from 8 float4 partials
    float salq[4], attq[4];
    float amn = INFINITY, amx = -INFINITY;
    if (tid < 196) {
        int idx0 = 4 * tid;
        int yo = idx0 / WF, x = idx0 - yo * WF;   // x in {0,4,...,24}
        float acc0 = 0.0f, acc1 = 0.0f, acc2 = 0.0f, acc3 = 0.0f, wsum = 0.0f;
        int j0 = 8 * yo - 4;
        #pragma unroll
        for (int t = 0; t < 16; t++) {
            int j = j0 + t;
            float w = 8.0f - fabsf((float)t - 7.5f);
            if ((unsigned)j < HIMG) {
                acc0 += w * hres[j][x];     acc1 += w * hres[j][x + 1];
                acc2 += w * hres[j][x + 2]; acc3 += w * hres[j][x + 3];
                wsum += w;
            }
        }
        float inv = 1.0f / wsum;
        salq[0] = vok ? (acc0 * inv - vmn) / vden : 0.5f;
        salq[1] = vok ? (acc1 * inv - vmn) / vden : 0.5f;
        salq[2] = vok ? (acc2 * inv - vmn) / vden : 0.5f;
        salq[3] = vok ? (acc3 * inv - vmn) / vden : 0.5f;

        const float* ap = ws + OFF_AP + (size_t)b * POS + idx0;
        float sx = 0.0f, sy = 0.0f, sz = 0.0f, sw = 0.0f;
        #pragma unroll
        for (int z = 0; z < 8; z++) {            // ascending z => c order 0..511
            f4v u = nt4(ap + (size_t)z * BATCH * POS);
            sx += u.x; sy += u.y; sz += u.z; sw += u.w;
        }
        attq[0] = sqrtf(sx * (1.0f / CF));
        attq[1] = sqrtf(sy * (1.0f / CF));
        attq[2] = sqrtf(sz * (1.0f / CF));
        attq[3] = sqrtf(sw * (1.0f / CF));
        #pragma unroll
        for (int l = 0; l < 4; l++) {
            amn = fminf(amn, attq[l]); amx = fmaxf(amx, attq[l]);
        }
    }

    // 4) block min/max of attn (single wred pass)
    #pragma unroll
    for (int o = 32; o > 0; o >>= 1) {
        amn = fminf(amn, __shfl_xor(amn, o));
        amx = fmaxf(amx, __shfl_xor(amx, o));
    }
    int w = tid >> 6;
    if ((tid & 63) == 0) { wred[w] = amn; wred[4 + w] = amx; }
    __syncthreads();
    if (tid == 0) {
        s_mn = fminf(fminf(wred[0], wred[1]), fminf(wred[2], wred[3]));
        s_mx = fmaxf(fmaxf(wred[4], wred[5]), fmaxf(wred[6], wred[7]));
    }
    __syncthreads();
    amn = s_mn; amx = s_mx;
    float aden = amx - amn;
    bool aok = aden > EPS_C;

    // 5) MSE partial
    float lsum = 0.0f;
    if (tid < 196) {
        #pragma unroll
        for (int l = 0; l < 4; l++) {
            float an = aok ? (attq[l] - amn) / aden : 0.5f;
            float d = an - salq[l];
            lsum += d * d;
        }
    }
    #pragma unroll
    for (int o = 32; o > 0; o >>= 1) lsum += __shfl_xor(lsum, o);
    if ((tid & 63) == 0) wred[w] = lsum;
    __syncthreads();

    // 6) accumulate across blocks; last finished block writes output
    if (tid == 0) {
        float part = wred[0] + wred[1] + wred[2] + wred[3];
        atomicAdd(ws + OFF_ACC, part);
        __threadfence();
        unsigned old = atomicAdd((unsigned*)ws + OFF_CNT, 1u);
        if (old == BATCH - 1) {
            float tot = atomicAdd(ws + OFF_ACC, 0.0f);  // device-coherent read
            out[0] = tot * (ALPHA_C / (float)(BATCH * POS));
        }
    }
}

extern "C" void kernel_launch(void* const* d_in, const int* in_sizes, int n_in,
                              void* d_out, int out_size, void* d_ws, size_t ws_size,
                              hipStream_t stream) {
    const float* features = (const float*)d_in[0];  // [64,512,28,28]
    const float* images   = (const float*)d_in[1];  // [64,3,224,224]
    float* ws  = (float*)d_ws;
    float* out = (float*)d_out;

    hipLaunchKernelGGL(fat_k,   dim3(NATTN + NVARH), dim3(256), 0, stream,
                       images, features, ws);
    hipLaunchKernelGGL(fused_k, dim3(BATCH),         dim3(256), 0, stream, ws, out);
}